// Round 7
// baseline (306.329 us; speedup 1.0000x reference)
//
#include <hip/hip_runtime.h>
#include <stdint.h>

#define ROUNDS 64
#define HIDDEN 256
#define BATCH  65536

typedef int   v4i  __attribute__((ext_vector_type(4)));
typedef int   v8i  __attribute__((ext_vector_type(8)));
typedef float v16f __attribute__((ext_vector_type(16)));

// ws layout: Wpk fp4 fragments [r][mt=8][ks=4][lane=64][16B] = 2 MB,
// then noise floats [r][mt=8][lh=2][j=16] f32 = 64 KB.
#define WPK_BYTES (ROUNDS * 8 * 4 * 64 * 16)

// sigma: nibble slot n (0..31) within a 32-k chunk holds logical k-offset
// rho(n). Rows (j&3)+8*(j>>2)+4*lh of the 32x32 C layout land in each lane's
// own contiguous 8 bytes -> 1 conflict-free ds_write_b64 epilogue. Applied
// identically to W-pack, state init, and unpack, so it cancels in the dot.
__host__ __device__ constexpr int rho(int n) {
  return 4 * (n >> 4) + (n & 3) + 8 * ((n >> 2) & 3);
}

// Per-C-slot bias, applied in the EPILOGUE (plain v_add_f32 — IEEE exact:
// value+1.5*2^{22-4q} stays in [2^e, 2^(e+1)), integer, ulp <= 0.5). NOTE
// round-1 FAILED experiment: bias folded into the MFMA C-init gives absmax
// 1.0 (f8f6f4 MFMA flushes the +-1 dot addends against a 2^22 C). Bias must
// stay OUTSIDE the MFMA; small noise (+-1) as C-init is proven fine (R3).
// Slot j (q = j&3) gets 1.5*2^{22-4q} -> parity bit lands at mantissa bit
// 4q+1, i.e. exactly the fp4-nibble bit-1 position for nibble q.
__host__ __device__ constexpr float bias_q(int q) {
  return (q == 0) ? 6291456.0f   // 1.5*2^22 -> parity at bit 1
       : (q == 1) ? 393216.0f    // 1.5*2^18 -> bit 5
       : (q == 2) ? 24576.0f     // 1.5*2^14 -> bit 9
                  : 1536.0f;     // 1.5*2^10 -> bit 13
}

// ---- pack W into fp4 A-fragments (blocks 0..511) and noise->f32 in
// C-layout row order (blocks 512..575) ----
__global__ __launch_bounds__(256) void pack_w4(const float* __restrict__ mat,
                                               const float* __restrict__ noi,
                                               uint32_t* __restrict__ wpk,
                                               float* __restrict__ nf) {
  if (blockIdx.x >= 512) {  // noise: nf[r][mt][lh][j] = noise[r][row(j,lh)+mt*32]
    unsigned tg = (blockIdx.x - 512) * 256u + threadIdx.x;  // < 16384
    unsigned j = tg & 15u, lh = (tg >> 4) & 1u, mt = (tg >> 5) & 7u, r = tg >> 8;
    unsigned row = mt * 32u + (j & 3u) + 8u * (j >> 2) + 4u * lh;
    nf[tg] = noi[r * 256u + row];
    return;
  }
  unsigned tg = blockIdx.x * 256u + threadIdx.x;  // (r*256+row)*8 + kwin
  unsigned kwin = tg & 7u;
  unsigned rr = tg >> 3;  // r*256 + row
  const float4* F4 = (const float4*)(mat + (size_t)rr * 256 + kwin * 32);
  float4 F[8];
#pragma unroll
  for (int i = 0; i < 8; ++i) F[i] = F4[i];
  const float* Ff = (const float*)F;
  uint32_t w[4] = {0, 0, 0, 0};
#pragma unroll
  for (int n = 0; n < 32; ++n) {
    uint32_t u = __builtin_bit_cast(uint32_t, Ff[rho(n)]);
    // fp4 e2m1: 0 -> 0b0000, +1 -> 0b0010, -1 -> 0b1010
    uint32_t nib = ((u & 0x7fffffffu) ? 2u : 0u) | ((u >> 28) & 8u);
    w[n >> 3] |= nib << ((n & 7) * 4);
  }
  unsigned r = rr >> 8, row = rr & 255u;
  unsigned mt = row >> 5, lh = kwin & 1u, ks = kwin >> 1;
  unsigned lane = lh * 32u + (row & 31u);
  *(uint4*)(wpk + ((((r * 8u + mt) * 4u + ks) * 64u + lane) << 2)) =
      make_uint4(w[0], w[1], w[2], w[3]);
}

// ---- main: 512 threads (8 waves), 128 el/block, 512 blocks (2 blocks/CU,
// 16 waves/CU — the occupancy that won R3-R6's scan). Wave tiling 2mt x 2tn
// (wave wv: mt {2(wv&3), 2(wv&3)+1} x tn {2(wv>>2), 2(wv>>2)+1}): B-fragment
// LDS reads halve vs R3's 1x4 (8 b128/round, each feeds 2 MFMAs). Register
// trick that makes this fit in the 128-reg budget (R4's wall): next round's
// NZ is preloaded INTO acc[mtt][0] (dead after the epilogue); at ks=0, tile
// tn=1 reads C from acc[mtt][0] BEFORE tn=0's in-place MFMA overwrites it.
// The NZ load issues right before __syncthreads, whose mandatory vmcnt(0)
// drain (already paid for the A-prefetch) covers its latency — this is the
// exposed-latency bug that sank R4, fixed.
// fp4 MFMA 32x32x64, K=256 in 4 steps, noise C-init, bias-const epilogue.
// State double-buffered in LDS [buf][KB=8][el=128][16B].
// NOTE: barrier is __syncthreads() — the raw lgkm-only s_barrier variant
// produced warm-state-dependent divergence (round-5 FAILED experiment).
__global__ __launch_bounds__(512, 4) void hash4(const uint32_t* __restrict__ wpk,
                                                const float* __restrict__ nf,
                                                const float* __restrict__ sta,
                                                float* __restrict__ out) {
  __shared__ uint8_t T[2][8][128][16];  // 32 KB
  const int t = threadIdx.x;
  const int wv = __builtin_amdgcn_readfirstlane(t >> 6);  // 0..7
  const int lane = t & 63;
  const int l31 = lane & 31;
  const int lh = lane >> 5;
  const int el0 = blockIdx.x * 128;
  const int mt0 = (wv & 3) * 2;   // this wave's M-tiles: mt0, mt0+1
  const int tn0 = (wv >> 2) * 2;  // this wave's N-tiles: tn0, tn0+1

  // ---- initial pack: f32 -> sigma-ordered fp4 nibbles (4 logical k per u16) ----
#pragma unroll
  for (int i = 0; i < 16; ++i) {
    unsigned flat = (unsigned)i * 512u + t;  // float4 idx in 128x256 slab
    unsigned el = flat >> 6, k4 = flat & 63u;
    float4 f = ((const float4*)(sta + (size_t)el0 * 256))[flat];
    uint32_t v = ((f.x != 0.f) ? 0x2u : 0u) | ((f.y != 0.f) ? 0x20u : 0u) |
                 ((f.z != 0.f) ? 0x200u : 0u) | ((f.w != 0.f) ? 0x2000u : 0u);
    unsigned KB = k4 >> 3, k4c = k4 & 7u;
    unsigned byteoff = (k4c & 1u) * 8u + 2u * (k4c >> 1);  // sigma^-1 of 4 rows
    *(uint16_t*)&T[0][KB][el][byteoff] = (uint16_t)v;
  }
  __syncthreads();

  // prefetch round-0 A fragments (2 mt x 4 ks); NZ(0) preloads into acc.
  v4i ap[2][4];
  v16f acc[2][2];
#pragma unroll
  for (int mtt = 0; mtt < 2; ++mtt) {
    const uint32_t* wb = wpk + (((mt0 + mtt) * 4) << 8);
#pragma unroll
    for (int ks = 0; ks < 4; ++ks) ap[mtt][ks] = *(const v4i*)(wb + ks * 256 + lane * 4);
    acc[mtt][0] = *(const v16f*)(nf + ((mt0 + mtt) * 2 + lh) * 16);
  }

#pragma unroll 2
  for (int r = 0; r < ROUNDS; ++r) {
    const int rb = r & 1, nx = rb ^ 1;
    __builtin_amdgcn_s_setprio(1);
#pragma unroll
    for (int ks = 0; ks < 4; ++ks) {
      const int kb = 2 * ks + lh;
      // fp4 fmt uses only regs 0..3 of the 8-reg operand: 4..7 stay undef.
      v8i A80 = __builtin_shufflevector(ap[0][ks], ap[0][ks], 0, 1, 2, 3, -1, -1, -1, -1);
      v8i A81 = __builtin_shufflevector(ap[1][ks], ap[1][ks], 0, 1, 2, 3, -1, -1, -1, -1);
      v4i b0 = *(const v4i*)&T[rb][kb][(tn0 + 0) * 32 + l31][0];  // conflict-free b128
      v4i b1 = *(const v4i*)&T[rb][kb][(tn0 + 1) * 32 + l31][0];
      v8i B0 = __builtin_shufflevector(b0, b0, 0, 1, 2, 3, -1, -1, -1, -1);
      v8i B1 = __builtin_shufflevector(b1, b1, 0, 1, 2, 3, -1, -1, -1, -1);
      if (ks == 0) {
        // acc[mtt][0] holds NZ; tn=1 must read it BEFORE tn=0 overwrites.
        acc[0][1] = __builtin_amdgcn_mfma_scale_f32_32x32x64_f8f6f4(
            A80, B1, acc[0][0], 4, 4, 0, 127, 0, 127);
        acc[0][0] = __builtin_amdgcn_mfma_scale_f32_32x32x64_f8f6f4(
            A80, B0, acc[0][0], 4, 4, 0, 127, 0, 127);
        acc[1][1] = __builtin_amdgcn_mfma_scale_f32_32x32x64_f8f6f4(
            A81, B1, acc[1][0], 4, 4, 0, 127, 0, 127);
        acc[1][0] = __builtin_amdgcn_mfma_scale_f32_32x32x64_f8f6f4(
            A81, B0, acc[1][0], 4, 4, 0, 127, 0, 127);
      } else {
        acc[0][0] = __builtin_amdgcn_mfma_scale_f32_32x32x64_f8f6f4(
            A80, B0, acc[0][0], 4, 4, 0, 127, 0, 127);
        acc[0][1] = __builtin_amdgcn_mfma_scale_f32_32x32x64_f8f6f4(
            A80, B1, acc[0][1], 4, 4, 0, 127, 0, 127);
        acc[1][0] = __builtin_amdgcn_mfma_scale_f32_32x32x64_f8f6f4(
            A81, B0, acc[1][0], 4, 4, 0, 127, 0, 127);
        acc[1][1] = __builtin_amdgcn_mfma_scale_f32_32x32x64_f8f6f4(
            A81, B1, acc[1][1], 4, 4, 0, 127, 0, 127);
      }
    }
    __builtin_amdgcn_s_setprio(0);

    // prefetch next round's A (r=63 wraps to 0 -> no OOB, dead value)
    const int rn = (r + 1) & 63;
#pragma unroll
    for (int mtt = 0; mtt < 2; ++mtt) {
      const uint32_t* wb = wpk + (((rn * 8 + mt0 + mtt) * 4) << 8);
#pragma unroll
      for (int ks = 0; ks < 4; ++ks)
        ap[mtt][ks] = *(const v4i*)(wb + ks * 256 + lane * 4);
    }

    // epilogue: bias-const add (exact) puts slot j's parity bit at mantissa
    // bit 4*(j&3)+1 == its target nibble-bit; mask + or-chain. After the
    // extraction acc is dead -> reload NZ(r+1) into acc[mtt][0]; the barrier's
    // vmcnt(0) drain covers its latency.
#pragma unroll
    for (int mtt = 0; mtt < 2; ++mtt) {
#pragma unroll
      for (int tnn = 0; tnn < 2; ++tnn) {
#define PB(j)                                                              \
  (__builtin_bit_cast(uint32_t, acc[mtt][tnn][j] + bias_q((j) & 3)) &      \
   (2u << (4 * ((j) & 3))))
        uint32_t u0 = PB(0) | PB(1) | PB(2) | PB(3);
        uint32_t u1 = PB(4) | PB(5) | PB(6) | PB(7);
        uint32_t u2 = PB(8) | PB(9) | PB(10) | PB(11);
        uint32_t u3 = PB(12) | PB(13) | PB(14) | PB(15);
#undef PB
        *(uint2*)&T[nx][mt0 + mtt][(tn0 + tnn) * 32 + l31][lh * 8] =
            make_uint2(u0 | (u1 << 16), u2 | (u3 << 16));
      }
      acc[mtt][0] = *(const v16f*)(nf + ((rn * 8 + mt0 + mtt) * 2 + lh) * 16);
    }

    __syncthreads();  // single barrier/round (double-buffered state)
  }

  // ---- final unpack: buf 0 holds the round-63 output ----
#pragma unroll
  for (int i = 0; i < 16; ++i) {
    unsigned flat = (unsigned)i * 512u + t;
    unsigned el = flat >> 6, k4 = flat & 63u;
    unsigned KB = k4 >> 3, k4c = k4 & 7u;
    unsigned byteoff = (k4c & 1u) * 8u + 2u * (k4c >> 1);
    uint32_t v = *(const uint16_t*)&T[0][KB][el][byteoff];
    float4 o = make_float4((float)((v >> 1) & 1u), (float)((v >> 5) & 1u),
                           (float)((v >> 9) & 1u), (float)((v >> 13) & 1u));
    ((float4*)(out + (size_t)el0 * 256))[flat] = o;
  }
}

extern "C" void kernel_launch(void* const* d_in, const int* in_sizes, int n_in,
                              void* d_out, int out_size, void* d_ws, size_t ws_size,
                              hipStream_t stream) {
  const float* sta = (const float*)d_in[0];  // [B, HIDDEN]
  const float* mat = (const float*)d_in[1];  // [ROUNDS, HIDDEN, HIDDEN]
  const float* noi = (const float*)d_in[2];  // [ROUNDS, HIDDEN]
  uint8_t* wsb = (uint8_t*)d_ws;             // needs ~2.07 MB

  pack_w4<<<576, 256, 0, stream>>>(mat, noi, (uint32_t*)wsb,
                                   (float*)(wsb + WPK_BYTES));
  hash4<<<512, 512, 0, stream>>>((const uint32_t*)wsb,
                                 (const float*)(wsb + WPK_BYTES), sta,
                                 (float*)d_out);
}

// Round 8
// 251.138 us; speedup vs baseline: 1.2198x; 1.2198x over previous
//
#include <hip/hip_runtime.h>
#include <stdint.h>

#define ROUNDS 64
#define HIDDEN 256
#define BATCH  65536

typedef int   v4i  __attribute__((ext_vector_type(4)));
typedef int   v8i  __attribute__((ext_vector_type(8)));
typedef float v16f __attribute__((ext_vector_type(16)));
typedef unsigned long long u64;

// ============================================================================
// ALGEBRAIC COLLAPSE: each round is s' = (W s + n) mod 2 over the integers.
// Mod 2 the ternary W equals the binary matrix Whar = (W != 0)  (-1 === 1 mod 2),
// so every round is an affine map over GF(2):  s' = Whar s XOR n.
// Affine maps compose: (B,b) o (A,a) = (B*A, B*a XOR b)  [apply (A,a) first].
// The full 64-round hash is ONE affine map: s_f = M s0 XOR c, with
//   M = W63*...*W0,  c = sum_r (W63*...*W_{r+1}) n_r   (all over GF(2)).
// We fold the 64 maps on-device (tree: 8 chains of 8, then 1 chain of 8),
// then apply M,c to the batch with the PROVEN single-round fp4-MFMA kernel.
// Exact: remainder(int,2) == bit0 (floored mod), parity algebra is exact.
// ============================================================================

// ws layout (bytes): all 64-aligned where needed
#define WB_OFF   0u        // W bits  [64][256][4] u64 = 512 KB
#define NB_OFF   524288u   // n bits  [64][4] u64      = 2 KB
#define G1M_OFF  526336u   // level-1 matrices [8][256][4] u64 = 64 KB
#define G1V_OFF  591872u   // level-1 vectors  [8][4] u64      = 256 B
#define FM_OFF   592128u   // final M [256][4] u64 = 8 KB
#define FV_OFF   600320u   // final c [4] u64      = 32 B
#define WPK_OFF  600384u   // fp4 A-fragments [mt=8][ks=4][lane=64][16B] = 32 KB
#define NF_OFF   633152u   // noise floats [mt=8][lh=2][j=16] f32 = 1 KB

// sigma: nibble slot n (0..31) within a 32-k chunk holds logical k-offset
// rho(n). Applied identically to M-pack and state-pack so it cancels.
__host__ __device__ constexpr int rho(int n) {
  return 4 * (n >> 4) + (n & 3) + 8 * ((n >> 2) & 3);
}

// Per-C-slot bias (epilogue v_add_f32, IEEE-exact; see round-1 FAILED note:
// bias must stay OUTSIDE the MFMA C-init). dot in [0,256] + c in {0,1}:
// q=0: 6291456+257 < 2^23 ; q=3: 1536+257 < 2^11 — exact for all slots.
__host__ __device__ constexpr float bias_q(int q) {
  return (q == 0) ? 6291456.0f   // 1.5*2^22 -> parity at bit 1
       : (q == 1) ? 393216.0f    // 1.5*2^18 -> bit 5
       : (q == 2) ? 24576.0f     // 1.5*2^14 -> bit 9
                  : 1536.0f;     // 1.5*2^10 -> bit 13
}

// ---- 1) bitpack: W floats -> row-major bit matrix; noise -> bit vectors ----
// Wb word index (r*256+i)*4 + w  holds bits k = 64w..64w+63 of row i, round r.
__global__ __launch_bounds__(256) void bitpack(const float* __restrict__ mat,
                                               const float* __restrict__ noi,
                                               u64* __restrict__ wb,
                                               u64* __restrict__ nb) {
  unsigned blk = blockIdx.x;
  if (blk >= 16384u) {  // noise: 64*256 bits
    unsigned tg = (blk - 16384u) * 256u + threadIdx.x;  // < 16384
    u64 m = __ballot(noi[tg] != 0.f);
    if ((threadIdx.x & 63u) == 0u) nb[tg >> 6] = m;
    return;
  }
  unsigned tg = blk * 256u + threadIdx.x;  // element index into [64][256][256]
  u64 m = __ballot(mat[tg] != 0.f);
  if ((threadIdx.x & 63u) == 0u) wb[tg >> 6] = m;
}

// ---- 2) fold: block b sequentially composes maps [b*chain, (b+1)*chain) ----
// State (A,a) starts as the FIRST map of the chain; each step composes the
// NEXT map (B,b): A <- B*A (GF2 matmul, 4-bit-table XOR method), a <- B*a ^ b.
// Thread layout: tid = w*256 + i (w = word 0..3, i = row 0..255). 1024 thr.
__global__ __launch_bounds__(1024) void fold(const u64* __restrict__ inM,
                                             const u64* __restrict__ inV,
                                             u64* __restrict__ outM,
                                             u64* __restrict__ outV,
                                             int chain) {
  __shared__ u64 A[256][5];       // padded (bank spread)
  __shared__ u64 tbl[64][16][5];  // tbl[c][m] = XOR of A rows {4c+j : bit j of m}
  __shared__ u64 avec[4];
  const int tid = threadIdx.x;
  const int w = tid >> 8;   // 0..3
  const int i = tid & 255;  // 0..255
  const int base = blockIdx.x * chain;

  A[i][w] = inM[(size_t)base * 1024 + i * 4 + w];
  if (tid < 4) avec[tid] = inV[base * 4 + tid];
  __syncthreads();

  for (int j = 1; j < chain; ++j) {
    const u64* Bm = inM + (size_t)(base + j) * 1024;
    u64 br[4];
#pragma unroll
    for (int q = 0; q < 4; ++q) br[q] = Bm[i * 4 + q];

    // build 4-bit combination table over A's rows (contraction index k)
    {
      const int c = tid >> 4, m = tid & 15;  // 64*16 = 1024 entries, 1/thread
      u64 t0 = 0, t1 = 0, t2 = 0, t3 = 0;
#pragma unroll
      for (int jj = 0; jj < 4; ++jj)
        if (m & (1 << jj)) {
          t0 ^= A[4 * c + jj][0]; t1 ^= A[4 * c + jj][1];
          t2 ^= A[4 * c + jj][2]; t3 ^= A[4 * c + jj][3];
        }
      tbl[c][m][0] = t0; tbl[c][m][1] = t1; tbl[c][m][2] = t2; tbl[c][m][3] = t3;
    }
    __syncthreads();

    // R[i] = XOR_{k: B[i][k]=1} A[k]   (i.e. (B*A) row i), word w
    u64 acc = 0;
#pragma unroll
    for (int c = 0; c < 64; ++c) {
      unsigned nib = (unsigned)(br[c >> 4] >> ((c & 15) * 4)) & 15u;
      acc ^= tbl[c][nib][w];
    }

    // a' = B*a ^ b : bit i = parity(popcount(Brow_i & a)) ^ b_i (waves 0..3)
    u64 mask = 0;
    if (tid < 256) {
      int p = __popcll(br[0] & avec[0]) + __popcll(br[1] & avec[1]) +
              __popcll(br[2] & avec[2]) + __popcll(br[3] & avec[3]);
      u64 bword = inV[(size_t)(base + j) * 4 + (i >> 6)];
      int bit = ((int)((bword >> (i & 63)) & 1ull)) ^ (p & 1);
      mask = __ballot(bit);
    }
    __syncthreads();  // tbl/avec reads done before overwrite
    A[i][w] = acc;
    if (tid < 256 && (i & 63) == 0) avec[i >> 6] = mask;
    __syncthreads();
  }

  outM[(size_t)blockIdx.x * 1024 + i * 4 + w] = A[i][w];
  if (tid < 4) outV[blockIdx.x * 4 + tid] = avec[tid];
}

// ---- 3) pack M bits -> fp4 A-fragments (blocks 0..7), c bits -> nf floats
// (block 8). Mirrors the proven pack_w4 layout exactly (r = 0 only). ----
__global__ __launch_bounds__(256) void packm(const u64* __restrict__ FM,
                                             const u64* __restrict__ FV,
                                             uint32_t* __restrict__ wpk,
                                             float* __restrict__ nf) {
  if (blockIdx.x == 8) {  // nf[mt][lh][j] = c[row(j,lh,mt)]
    unsigned tid = threadIdx.x;
    unsigned j = tid & 15u, lh = (tid >> 4) & 1u, mt = tid >> 5;
    unsigned row = mt * 32u + (j & 3u) + 8u * (j >> 2) + 4u * lh;
    nf[tid] = (float)((FV[row >> 6] >> (row & 63u)) & 1ull);
    return;
  }
  unsigned tg = blockIdx.x * 256u + threadIdx.x;  // row*8 + kwin
  unsigned kwin = tg & 7u, row = tg >> 3;
  const u64* Mr = FM + row * 4;
  uint32_t w[4] = {0, 0, 0, 0};
#pragma unroll
  for (int n = 0; n < 32; ++n) {
    int k = (int)kwin * 32 + rho(n);
    uint32_t bit = (uint32_t)((Mr[k >> 6] >> (k & 63)) & 1ull);
    // fp4 e2m1: 0 -> 0b0000, +1 -> 0b0010  (M is {0,1}: no sign bit needed)
    w[n >> 3] |= (bit * 2u) << ((n & 7) * 4);
  }
  unsigned mt = row >> 5, lh = kwin & 1u, ks = kwin >> 1;
  unsigned lane = lh * 32u + (row & 31u);
  *(uint4*)(wpk + (((mt * 4u + ks) * 64u + lane) << 2)) =
      make_uint4(w[0], w[1], w[2], w[3]);
}

// ---- 4) hash1: the PROVEN R3 hash4 structure with exactly ONE round.
// out = (M s0 + c) mod 2 via fp4 MFMA 32x32x64, K=256 in 4 steps, c as MFMA
// C-init, bias-trick epilogue. 512 thr, 128 el/block, wave wv = M-tile wv. ----
__global__ __launch_bounds__(512, 4) void hash1(const uint32_t* __restrict__ wpk,
                                                const float* __restrict__ nf,
                                                const float* __restrict__ sta,
                                                float* __restrict__ out) {
  __shared__ uint8_t T[2][8][128][16];  // 32 KB
  const int t = threadIdx.x;
  const int wv = __builtin_amdgcn_readfirstlane(t >> 6);
  const int lane = t & 63;
  const int l31 = lane & 31;
  const int lh = lane >> 5;
  const int el0 = blockIdx.x * 128;

  // initial pack: f32 -> sigma-ordered fp4 nibbles into T[0]
#pragma unroll
  for (int i = 0; i < 16; ++i) {
    unsigned flat = (unsigned)i * 512u + t;
    unsigned el = flat >> 6, k4 = flat & 63u;
    float4 f = ((const float4*)(sta + (size_t)el0 * 256))[flat];
    uint32_t v = ((f.x != 0.f) ? 0x2u : 0u) | ((f.y != 0.f) ? 0x20u : 0u) |
                 ((f.z != 0.f) ? 0x200u : 0u) | ((f.w != 0.f) ? 0x2000u : 0u);
    unsigned KB = k4 >> 3, k4c = k4 & 7u;
    unsigned byteoff = (k4c & 1u) * 8u + 2u * (k4c >> 1);
    *(uint16_t*)&T[0][KB][el][byteoff] = (uint16_t)v;
  }
  __syncthreads();

  v4i ap[4];
  {
    const uint32_t* wb = wpk + ((wv * 4) << 8);
#pragma unroll
    for (int ks = 0; ks < 4; ++ks) ap[ks] = *(const v4i*)(wb + ks * 256 + lane * 4);
  }
  v16f NZ = *(const v16f*)(nf + (wv * 2 + lh) * 16);

  v16f acc[4];
  __builtin_amdgcn_s_setprio(1);
#pragma unroll
  for (int ks = 0; ks < 4; ++ks) {
    v8i A8 = __builtin_shufflevector(ap[ks], ap[ks], 0, 1, 2, 3, -1, -1, -1, -1);
    const int kb = 2 * ks + lh;
#pragma unroll
    for (int tn = 0; tn < 4; ++tn) {
      v4i b4 = *(const v4i*)&T[0][kb][tn * 32 + l31][0];
      v8i B8 = __builtin_shufflevector(b4, b4, 0, 1, 2, 3, -1, -1, -1, -1);
      acc[tn] = __builtin_amdgcn_mfma_scale_f32_32x32x64_f8f6f4(
          A8, B8, (ks == 0) ? NZ : acc[tn], 4, 4, 0, 127, 0, 127);
    }
  }
  __builtin_amdgcn_s_setprio(0);

  // epilogue -> T[1]
#pragma unroll
  for (int tn = 0; tn < 4; ++tn) {
#define PB(j)                                                          \
  (__builtin_bit_cast(uint32_t, acc[tn][j] + bias_q((j) & 3)) &        \
   (2u << (4 * ((j) & 3))))
    uint32_t u0 = PB(0) | PB(1) | PB(2) | PB(3);
    uint32_t u1 = PB(4) | PB(5) | PB(6) | PB(7);
    uint32_t u2 = PB(8) | PB(9) | PB(10) | PB(11);
    uint32_t u3 = PB(12) | PB(13) | PB(14) | PB(15);
#undef PB
    *(uint2*)&T[1][wv][tn * 32 + l31][lh * 8] =
        make_uint2(u0 | (u1 << 16), u2 | (u3 << 16));
  }
  __syncthreads();

  // unpack T[1] -> out
#pragma unroll
  for (int i = 0; i < 16; ++i) {
    unsigned flat = (unsigned)i * 512u + t;
    unsigned el = flat >> 6, k4 = flat & 63u;
    unsigned KB = k4 >> 3, k4c = k4 & 7u;
    unsigned byteoff = (k4c & 1u) * 8u + 2u * (k4c >> 1);
    uint32_t v = *(const uint16_t*)&T[1][KB][el][byteoff];
    float4 o = make_float4((float)((v >> 1) & 1u), (float)((v >> 5) & 1u),
                           (float)((v >> 9) & 1u), (float)((v >> 13) & 1u));
    ((float4*)(out + (size_t)el0 * 256))[flat] = o;
  }
}

extern "C" void kernel_launch(void* const* d_in, const int* in_sizes, int n_in,
                              void* d_out, int out_size, void* d_ws, size_t ws_size,
                              hipStream_t stream) {
  const float* sta = (const float*)d_in[0];  // [B, HIDDEN]
  const float* mat = (const float*)d_in[1];  // [ROUNDS, HIDDEN, HIDDEN]
  const float* noi = (const float*)d_in[2];  // [ROUNDS, HIDDEN]
  uint8_t* wsb = (uint8_t*)d_ws;             // needs ~640 KB

  u64* Wb       = (u64*)(wsb + WB_OFF);
  u64* nb       = (u64*)(wsb + NB_OFF);
  u64* G1M      = (u64*)(wsb + G1M_OFF);
  u64* G1V      = (u64*)(wsb + G1V_OFF);
  u64* FM       = (u64*)(wsb + FM_OFF);
  u64* FV       = (u64*)(wsb + FV_OFF);
  uint32_t* wpk = (uint32_t*)(wsb + WPK_OFF);
  float* nf     = (float*)(wsb + NF_OFF);

  bitpack<<<16448, 256, 0, stream>>>(mat, noi, Wb, nb);
  fold<<<8, 1024, 0, stream>>>(Wb, nb, G1M, G1V, 8);   // 8 chains of 8 rounds
  fold<<<1, 1024, 0, stream>>>(G1M, G1V, FM, FV, 8);   // fold the 8 partials
  packm<<<9, 256, 0, stream>>>(FM, FV, wpk, nf);
  hash1<<<512, 512, 0, stream>>>(wpk, nf, sta, (float*)d_out);
}

// Round 9
// 225.691 us; speedup vs baseline: 1.3573x; 1.1128x over previous
//
#include <hip/hip_runtime.h>
#include <stdint.h>

#define ROUNDS 64
#define HIDDEN 256
#define BATCH  65536

typedef int   v4i  __attribute__((ext_vector_type(4)));
typedef int   v8i  __attribute__((ext_vector_type(8)));
typedef float v16f __attribute__((ext_vector_type(16)));
typedef unsigned long long u64;

// ============================================================================
// ALGEBRAIC COLLAPSE (R8, verified exact): each round is an affine map over
// GF(2): s' = Whar s XOR n (Whar = (W!=0), since -1 === 1 mod 2). Compose all
// 64: s_f = M s0 XOR c. Fold tree on-device, then apply (M,c) to the batch
// with the proven single-round fp4-MFMA kernel.
// R8 profile: fold was 2x61us at 0.67% VALUBusy — latency-bound on the
// serial 64-step XOR-gather chain and a 14-compose critical path. R9: 4-way
// ILP accumulators + 3-level tree (16x4 -> 4x4 -> 1x4, 9 composes critical).
// ============================================================================

// ws layout (bytes)
#define WB_OFF   0u        // W bits  [64][256][4] u64 = 512 KB
#define NB_OFF   524288u   // n bits  [64][4] u64      = 2 KB
#define G1M_OFF  526336u   // level-1 matrices [16][256][4] u64 = 128 KB
#define G1V_OFF  657408u   // level-1 vectors  [16][4] u64      = 512 B
#define G2M_OFF  657920u   // level-2 matrices [4][256][4] u64  = 32 KB
#define G2V_OFF  690688u   // level-2 vectors  [4][4] u64       = 128 B
#define FM_OFF   690816u   // final M [256][4] u64 = 8 KB
#define FV_OFF   699008u   // final c [4] u64      = 32 B
#define WPK_OFF  699072u   // fp4 A-fragments [mt=8][ks=4][lane=64][16B] = 32 KB
#define NF_OFF   731840u   // noise floats [mt=8][lh=2][j=16] f32 = 1 KB

// sigma: nibble slot n (0..31) within a 32-k chunk holds logical k-offset
// rho(n). Applied identically to M-pack and state-pack so it cancels.
__host__ __device__ constexpr int rho(int n) {
  return 4 * (n >> 4) + (n & 3) + 8 * ((n >> 2) & 3);
}

// Per-C-slot bias (epilogue v_add_f32, IEEE-exact; round-1 FAILED note: bias
// must stay OUTSIDE the MFMA C-init). dot in [0,256] + c in {0,1}: exact.
__host__ __device__ constexpr float bias_q(int q) {
  return (q == 0) ? 6291456.0f   // 1.5*2^22 -> parity at bit 1
       : (q == 1) ? 393216.0f    // 1.5*2^18 -> bit 5
       : (q == 2) ? 24576.0f     // 1.5*2^14 -> bit 9
                  : 1536.0f;     // 1.5*2^10 -> bit 13
}

// ---- 1) bitpack: W floats -> row-major bit matrix; noise -> bit vectors ----
__global__ __launch_bounds__(256) void bitpack(const float* __restrict__ mat,
                                               const float* __restrict__ noi,
                                               u64* __restrict__ wb,
                                               u64* __restrict__ nb) {
  unsigned blk = blockIdx.x;
  if (blk >= 16384u) {  // noise: 64*256 bits
    unsigned tg = (blk - 16384u) * 256u + threadIdx.x;  // < 16384
    u64 m = __ballot(noi[tg] != 0.f);
    if ((threadIdx.x & 63u) == 0u) nb[tg >> 6] = m;
    return;
  }
  unsigned tg = blk * 256u + threadIdx.x;  // element index into [64][256][256]
  u64 m = __ballot(mat[tg] != 0.f);
  if ((threadIdx.x & 63u) == 0u) wb[tg >> 6] = m;
}

// ---- 2) fold: block b sequentially composes maps [b*chain, (b+1)*chain) ----
// State (A,a) starts as the FIRST map of the chain; each step composes the
// NEXT map (B,b): A <- B*A (GF2 matmul, 4-bit-table XOR), a <- B*a ^ b.
// Thread layout: tid = w*256 + i (w = word 0..3, i = row 0..255). 1024 thr.
// R9: 4 independent XOR accumulators break the 64-long serial gather chain.
__global__ __launch_bounds__(1024) void fold(const u64* __restrict__ inM,
                                             const u64* __restrict__ inV,
                                             u64* __restrict__ outM,
                                             u64* __restrict__ outV,
                                             int chain) {
  __shared__ u64 A[256][5];       // padded (bank spread)
  __shared__ u64 tbl[64][16][5];  // tbl[c][m] = XOR of A rows {4c+j : bit j of m}
  __shared__ u64 avec[4];
  const int tid = threadIdx.x;
  const int w = tid >> 8;   // 0..3
  const int i = tid & 255;  // 0..255
  const int base = blockIdx.x * chain;

  A[i][w] = inM[(size_t)base * 1024 + i * 4 + w];
  if (tid < 4) avec[tid] = inV[base * 4 + tid];
  __syncthreads();

  for (int j = 1; j < chain; ++j) {
    const u64* Bm = inM + (size_t)(base + j) * 1024;
    u64 br[4];
#pragma unroll
    for (int q = 0; q < 4; ++q) br[q] = Bm[i * 4 + q];
    // hoist the vector-update operand loads (overlap with table build)
    u64 bword = (tid < 256) ? inV[(size_t)(base + j) * 4 + (i >> 6)] : 0ull;
    u64 av0 = avec[0], av1 = avec[1], av2 = avec[2], av3 = avec[3];

    // build 4-bit combination table over A's rows (contraction index k)
    {
      const int c = tid >> 4, m = tid & 15;  // 64*16 = 1024 entries, 1/thread
      u64 t0 = 0, t1 = 0, t2 = 0, t3 = 0;
#pragma unroll
      for (int jj = 0; jj < 4; ++jj)
        if (m & (1 << jj)) {
          t0 ^= A[4 * c + jj][0]; t1 ^= A[4 * c + jj][1];
          t2 ^= A[4 * c + jj][2]; t3 ^= A[4 * c + jj][3];
        }
      tbl[c][m][0] = t0; tbl[c][m][1] = t1; tbl[c][m][2] = t2; tbl[c][m][3] = t3;
    }
    __syncthreads();

    // R[i] = XOR_{k: B[i][k]=1} A[k], word w — 4-way ILP over the 64 gathers
    u64 a0 = 0, a1 = 0, a2 = 0, a3 = 0;
#pragma unroll
    for (int c = 0; c < 64; c += 4) {
      unsigned n0 = (unsigned)(br[(c + 0) >> 4] >> (((c + 0) & 15) * 4)) & 15u;
      unsigned n1 = (unsigned)(br[(c + 1) >> 4] >> (((c + 1) & 15) * 4)) & 15u;
      unsigned n2 = (unsigned)(br[(c + 2) >> 4] >> (((c + 2) & 15) * 4)) & 15u;
      unsigned n3 = (unsigned)(br[(c + 3) >> 4] >> (((c + 3) & 15) * 4)) & 15u;
      a0 ^= tbl[c + 0][n0][w];
      a1 ^= tbl[c + 1][n1][w];
      a2 ^= tbl[c + 2][n2][w];
      a3 ^= tbl[c + 3][n3][w];
    }
    u64 acc = (a0 ^ a1) ^ (a2 ^ a3);

    // a' = B*a ^ b : bit i = parity(popcount(Brow_i & a)) ^ b_i (waves 0..3)
    u64 mask = 0;
    if (tid < 256) {
      int p = __popcll(br[0] & av0) + __popcll(br[1] & av1) +
              __popcll(br[2] & av2) + __popcll(br[3] & av3);
      int bit = ((int)((bword >> (i & 63)) & 1ull)) ^ (p & 1);
      mask = __ballot(bit);
    }
    __syncthreads();  // tbl/avec reads done before overwrite
    A[i][w] = acc;
    if (tid < 256 && (i & 63) == 0) avec[i >> 6] = mask;
    __syncthreads();
  }

  outM[(size_t)blockIdx.x * 1024 + i * 4 + w] = A[i][w];
  if (tid < 4) outV[blockIdx.x * 4 + tid] = avec[tid];
}

// ---- 3) pack M bits -> fp4 A-fragments (blocks 0..7), c bits -> nf floats
// (block 8). Mirrors the proven pack_w4 layout exactly (r = 0 only). ----
__global__ __launch_bounds__(256) void packm(const u64* __restrict__ FM,
                                             const u64* __restrict__ FV,
                                             uint32_t* __restrict__ wpk,
                                             float* __restrict__ nf) {
  if (blockIdx.x == 8) {  // nf[mt][lh][j] = c[row(j,lh,mt)]
    unsigned tid = threadIdx.x;
    unsigned j = tid & 15u, lh = (tid >> 4) & 1u, mt = tid >> 5;
    unsigned row = mt * 32u + (j & 3u) + 8u * (j >> 2) + 4u * lh;
    nf[tid] = (float)((FV[row >> 6] >> (row & 63u)) & 1ull);
    return;
  }
  unsigned tg = blockIdx.x * 256u + threadIdx.x;  // row*8 + kwin
  unsigned kwin = tg & 7u, row = tg >> 3;
  const u64* Mr = FM + row * 4;
  uint32_t w[4] = {0, 0, 0, 0};
#pragma unroll
  for (int n = 0; n < 32; ++n) {
    int k = (int)kwin * 32 + rho(n);
    uint32_t bit = (uint32_t)((Mr[k >> 6] >> (k & 63)) & 1ull);
    // fp4 e2m1: 0 -> 0b0000, +1 -> 0b0010  (M is {0,1}: no sign bit needed)
    w[n >> 3] |= (bit * 2u) << ((n & 7) * 4);
  }
  unsigned mt = row >> 5, lh = kwin & 1u, ks = kwin >> 1;
  unsigned lane = lh * 32u + (row & 31u);
  *(uint4*)(wpk + (((mt * 4u + ks) * 64u + lane) << 2)) =
      make_uint4(w[0], w[1], w[2], w[3]);
}

// ---- 4) hash1: the PROVEN R3 hash4 structure with exactly ONE round.
// out = (M s0 + c) mod 2 via fp4 MFMA 32x32x64, K=256 in 4 steps, c as MFMA
// C-init, bias-trick epilogue. 512 thr, 128 el/block, wave wv = M-tile wv. ----
__global__ __launch_bounds__(512, 4) void hash1(const uint32_t* __restrict__ wpk,
                                                const float* __restrict__ nf,
                                                const float* __restrict__ sta,
                                                float* __restrict__ out) {
  __shared__ uint8_t T[2][8][128][16];  // 32 KB
  const int t = threadIdx.x;
  const int wv = __builtin_amdgcn_readfirstlane(t >> 6);
  const int lane = t & 63;
  const int l31 = lane & 31;
  const int lh = lane >> 5;
  const int el0 = blockIdx.x * 128;

  // initial pack: f32 -> sigma-ordered fp4 nibbles into T[0]
#pragma unroll
  for (int i = 0; i < 16; ++i) {
    unsigned flat = (unsigned)i * 512u + t;
    unsigned el = flat >> 6, k4 = flat & 63u;
    float4 f = ((const float4*)(sta + (size_t)el0 * 256))[flat];
    uint32_t v = ((f.x != 0.f) ? 0x2u : 0u) | ((f.y != 0.f) ? 0x20u : 0u) |
                 ((f.z != 0.f) ? 0x200u : 0u) | ((f.w != 0.f) ? 0x2000u : 0u);
    unsigned KB = k4 >> 3, k4c = k4 & 7u;
    unsigned byteoff = (k4c & 1u) * 8u + 2u * (k4c >> 1);
    *(uint16_t*)&T[0][KB][el][byteoff] = (uint16_t)v;
  }
  __syncthreads();

  v4i ap[4];
  {
    const uint32_t* wb = wpk + ((wv * 4) << 8);
#pragma unroll
    for (int ks = 0; ks < 4; ++ks) ap[ks] = *(const v4i*)(wb + ks * 256 + lane * 4);
  }
  v16f NZ = *(const v16f*)(nf + (wv * 2 + lh) * 16);

  v16f acc[4];
  __builtin_amdgcn_s_setprio(1);
#pragma unroll
  for (int ks = 0; ks < 4; ++ks) {
    v8i A8 = __builtin_shufflevector(ap[ks], ap[ks], 0, 1, 2, 3, -1, -1, -1, -1);
    const int kb = 2 * ks + lh;
#pragma unroll
    for (int tn = 0; tn < 4; ++tn) {
      v4i b4 = *(const v4i*)&T[0][kb][tn * 32 + l31][0];
      v8i B8 = __builtin_shufflevector(b4, b4, 0, 1, 2, 3, -1, -1, -1, -1);
      acc[tn] = __builtin_amdgcn_mfma_scale_f32_32x32x64_f8f6f4(
          A8, B8, (ks == 0) ? NZ : acc[tn], 4, 4, 0, 127, 0, 127);
    }
  }
  __builtin_amdgcn_s_setprio(0);

  // epilogue -> T[1]
#pragma unroll
  for (int tn = 0; tn < 4; ++tn) {
#define PB(j)                                                          \
  (__builtin_bit_cast(uint32_t, acc[tn][j] + bias_q((j) & 3)) &        \
   (2u << (4 * ((j) & 3))))
    uint32_t u0 = PB(0) | PB(1) | PB(2) | PB(3);
    uint32_t u1 = PB(4) | PB(5) | PB(6) | PB(7);
    uint32_t u2 = PB(8) | PB(9) | PB(10) | PB(11);
    uint32_t u3 = PB(12) | PB(13) | PB(14) | PB(15);
#undef PB
    *(uint2*)&T[1][wv][tn * 32 + l31][lh * 8] =
        make_uint2(u0 | (u1 << 16), u2 | (u3 << 16));
  }
  __syncthreads();

  // unpack T[1] -> out
#pragma unroll
  for (int i = 0; i < 16; ++i) {
    unsigned flat = (unsigned)i * 512u + t;
    unsigned el = flat >> 6, k4 = flat & 63u;
    unsigned KB = k4 >> 3, k4c = k4 & 7u;
    unsigned byteoff = (k4c & 1u) * 8u + 2u * (k4c >> 1);
    uint32_t v = *(const uint16_t*)&T[1][KB][el][byteoff];
    float4 o = make_float4((float)((v >> 1) & 1u), (float)((v >> 5) & 1u),
                           (float)((v >> 9) & 1u), (float)((v >> 13) & 1u));
    ((float4*)(out + (size_t)el0 * 256))[flat] = o;
  }
}

extern "C" void kernel_launch(void* const* d_in, const int* in_sizes, int n_in,
                              void* d_out, int out_size, void* d_ws, size_t ws_size,
                              hipStream_t stream) {
  const float* sta = (const float*)d_in[0];  // [B, HIDDEN]
  const float* mat = (const float*)d_in[1];  // [ROUNDS, HIDDEN, HIDDEN]
  const float* noi = (const float*)d_in[2];  // [ROUNDS, HIDDEN]
  uint8_t* wsb = (uint8_t*)d_ws;             // needs ~733 KB

  u64* Wb       = (u64*)(wsb + WB_OFF);
  u64* nb       = (u64*)(wsb + NB_OFF);
  u64* G1M      = (u64*)(wsb + G1M_OFF);
  u64* G1V      = (u64*)(wsb + G1V_OFF);
  u64* G2M      = (u64*)(wsb + G2M_OFF);
  u64* G2V      = (u64*)(wsb + G2V_OFF);
  u64* FM       = (u64*)(wsb + FM_OFF);
  u64* FV       = (u64*)(wsb + FV_OFF);
  uint32_t* wpk = (uint32_t*)(wsb + WPK_OFF);
  float* nf     = (float*)(wsb + NF_OFF);

  bitpack<<<16448, 256, 0, stream>>>(mat, noi, Wb, nb);
  fold<<<16, 1024, 0, stream>>>(Wb, nb, G1M, G1V, 4);   // 16 chains of 4
  fold<<<4, 1024, 0, stream>>>(G1M, G1V, G2M, G2V, 4);  // 4 chains of 4
  fold<<<1, 1024, 0, stream>>>(G2M, G2V, FM, FV, 4);    // final 4
  packm<<<9, 256, 0, stream>>>(FM, FV, wpk, nf);
  hash1<<<512, 512, 0, stream>>>(wpk, nf, sta, (float*)d_out);
}